// Round 2
// baseline (74938.971 us; speedup 1.0000x reference)
//
#include <hip/hip_runtime.h>
#include <hip/hip_bf16.h>
#include <hip/hip_fp16.h>

// Persistent pipelined LSTM decoder. B=64, E=H=1024, 4H=4096, T=1024, L=3, O=64.
// One block per CU (256 blocks x 256 threads), weights register-resident.
// Pipeline (step s): L0 fin t=s | G1(Wih1) partial t=s-1 | L1 fin t=s-2 |
// G3(Wih2) partial t=s-3 | L2 fin t=s-4 | proj t=s-5.  1029 steps, 1 grid barrier each.
// All h reads use slot (s+1)&1, h writes slot s&1; p reads slot s&1, writes (s+1)&1.

typedef _Float16 v8h __attribute__((ext_vector_type(8)));
typedef _Float16 v4h __attribute__((ext_vector_type(4)));
typedef float v4f __attribute__((ext_vector_type(4)));

#define NSTEPS 1029

__global__ void cvt4_kernel(const float* __restrict__ s, _Float16* __restrict__ d, int n4) {
    int i = blockIdx.x * blockDim.x + threadIdx.x;
    int stride = gridDim.x * blockDim.x;
    for (; i < n4; i += stride) {
        v4f v = ((const v4f*)s)[i];
        v4h o;
        o[0] = (_Float16)v[0]; o[1] = (_Float16)v[1];
        o[2] = (_Float16)v[2]; o[3] = (_Float16)v[3];
        ((v4h*)d)[i] = o;
    }
}

// hbuf [3 layer][2 slot][64 b][1024 j] f16; slot1 = h[-1]
__global__ void hinit_kernel(const float* __restrict__ h0, _Float16* __restrict__ hbuf) {
    int i = blockIdx.x * 256 + threadIdx.x;   // 768*256 = 196608
    int l = i >> 16, rem = i & 65535;
    hbuf[(l * 2 + 1) * 65536 + rem] = (_Float16)h0[i];
}

__global__ void zcnt_kernel(unsigned* cnt) { if (threadIdx.x == 0) cnt[0] = 0u; }

// xp0[b][g] = enc @ Wih0^T + b_ih0 + b_hh0  (validated in R1)
__global__ __launch_bounds__(256) void xp0_kernel(
    const _Float16* __restrict__ enc16, const _Float16* __restrict__ Wih,
    const float* __restrict__ b_ih, const float* __restrict__ b_hh,
    float* __restrict__ xp0) {
    __shared__ float red[16384];
    const int tid = threadIdx.x, bx = blockIdx.x;
    const int ln = tid & 63, w = tid >> 6, lm = ln & 15, q = ln >> 4;
    v4f acc[4][4] = {};
    for (int kb = 0; kb < 8; ++kb) {
        int kk = (w + 4 * kb) * 32 + q * 8;
        v8h af[4], bf[4];
#pragma unroll
        for (int mt = 0; mt < 4; ++mt) af[mt] = *(const v8h*)(enc16 + (mt * 16 + lm) * 1024 + kk);
#pragma unroll
        for (int nt = 0; nt < 4; ++nt) bf[nt] = *(const v8h*)(Wih + (bx * 64 + nt * 16 + lm) * 1024 + kk);
#pragma unroll
        for (int mt = 0; mt < 4; ++mt)
#pragma unroll
            for (int nt = 0; nt < 4; ++nt)
                acc[mt][nt] = __builtin_amdgcn_mfma_f32_16x16x32_f16(af[mt], bf[nt], acc[mt][nt], 0, 0, 0);
    }
#pragma unroll
    for (int mt = 0; mt < 4; ++mt) if (mt != w)
#pragma unroll
        for (int nt = 0; nt < 4; ++nt)
            *(v4f*)&red[((w * 16 + mt * 4 + nt) * 64 + ln) * 4] = acc[mt][nt];
    __syncthreads();
#pragma unroll
    for (int ww = 0; ww < 4; ++ww) if (ww != w)
#pragma unroll
        for (int nt = 0; nt < 4; ++nt)
            acc[w][nt] += *(const v4f*)&red[((ww * 16 + w * 4 + nt) * 64 + ln) * 4];
#pragma unroll
    for (int nt = 0; nt < 4; ++nt) {
        int g = bx * 64 + nt * 16 + lm;
        float bb = b_ih[g] + b_hh[g];
#pragma unroll
        for (int r = 0; r < 4; ++r) {
            int b = w * 16 + q * 4 + r;
            xp0[b * 4096 + g] = acc[w][nt][r] + bb;
        }
    }
}

__global__ __launch_bounds__(256, 1) void lstm_persist(
    const _Float16* __restrict__ Wih16,   // [3][4096][1024]
    const _Float16* __restrict__ Whh16,   // [3][4096][1024]
    const _Float16* __restrict__ Wlin16,  // [64][1024]
    const float* __restrict__ xp0,        // [64][4096]
    const float* __restrict__ b_ih,       // [3][4096]
    const float* __restrict__ b_hh,       // [3][4096]
    const float* __restrict__ c0,         // [3][64][1024]
    const float* __restrict__ blin,       // [64]
    _Float16* __restrict__ hbuf,          // [3][2][64][1024]
    _Float16* __restrict__ pbuf,          // [2 layer][2 slot][64][4096]
    float* __restrict__ out,              // [64][1024][64]
    unsigned* __restrict__ cnt)
{
    __shared__ v4f red[3072];  // 48 KB: [3 u][4 dst][4 src][64 ln]
    const int b = blockIdx.x, tid = threadIdx.x;
    const int ln = tid & 63, w = tid >> 6, lm = ln & 15, q = ln >> 4;

    // ---------------- role resolution (uniform scalars) ----------------
    const bool isFin = b < 192;
    const int l = b >> 6;          // finisher layer (only meaningful if isFin)
    const int hs = b & 63;
    int nu;
    int sid[6];                    // single id; -1 = finisher chunk, -2 = off
    if (isFin) {
        nu = 5;
        sid[0] = sid[1] = sid[2] = sid[3] = -1;
        int s4;
        if (b < 64) s4 = b;                       // G1 tile b
        else if (b < 128) s4 = 256 + (b - 64);    // G3 tile b-64
        else if (b < 132) s4 = 512 + (b - 128);   // proj tile
        else s4 = b - 68;                         // pool[b-132] = G1 tile 64+(b-132)
        sid[4] = s4; sid[5] = -2;
    } else {
        int j = b - 192;
        int i0 = (b < 252) ? 60 + 5 * j : 360 + 6 * (b - 252);
        nu = (b < 252) ? 5 : 6;
#pragma unroll
        for (int u = 0; u < 6; ++u) {
            int i = i0 + u;
            sid[u] = (u < nu) ? ((i < 192) ? 64 + i : 128 + i) : -2;
        }
    }
    const _Float16* wbase[6]; int asel[6], lo[6], hi[6], pcol[6], pl[6]; bool prj[6];
#pragma unroll
    for (int u = 0; u < 6; ++u) {
        int sd = sid[u];
        if (isFin && u < 4) {
            wbase[u] = Whh16 + l * 4194304 + (u * 1024 + hs * 16) * 1024;
            asel[u] = l; lo[u] = 2 * l; hi[u] = 1024 + 2 * l;
            pcol[u] = 0; pl[u] = 0; prj[u] = false;
        } else if (sd >= 0) {
            if (sd < 256) {        // G1: Wih layer1, A=h0, t=s-1
                wbase[u] = Wih16 + 4194304 + sd * 16384;
                asel[u] = 0; lo[u] = 1; hi[u] = 1025; pcol[u] = sd * 16; pl[u] = 0; prj[u] = false;
            } else if (sd < 512) { // G3: Wih layer2, A=h1, t=s-3
                int T = sd - 256;
                wbase[u] = Wih16 + 2 * 4194304 + T * 16384;
                asel[u] = 1; lo[u] = 3; hi[u] = 1027; pcol[u] = T * 16; pl[u] = 1; prj[u] = false;
            } else {               // proj: Wlin, A=h2, t=s-5
                int T = sd - 512;
                wbase[u] = Wlin16 + T * 16384;
                asel[u] = 2; lo[u] = 5; hi[u] = 1029; pcol[u] = T * 16; pl[u] = 0; prj[u] = true;
            }
        } else {  // inactive: clone unit0, empty window
            wbase[u] = (isFin ? (Whh16 + l * 4194304 + (hs * 16) * 1024) : wbase[0]);
            asel[u] = asel[0]; lo[u] = 1 << 30; hi[u] = 0; pcol[u] = 0; pl[u] = 0; prj[u] = false;
        }
    }
    const int aselP = asel[0];
    bool useS[6]; bool anyS = false; int aselS = aselP;
#pragma unroll
    for (int u = 0; u < 6; ++u) {
        useS[u] = (asel[u] != aselP);
        if (useS[u]) { aselS = asel[u]; anyS = true; }
    }

    // ---------------- weight fragments -> registers (once) ----------------
    const int kofs = w * 256 + q * 8;   // this wave's K-quarter, lane k offset
    v8h wf[6][8];
#pragma unroll
    for (int u = 0; u < 6; ++u) {
        const _Float16* wr = wbase[u] + lm * 1024 + kofs;
#pragma unroll
        for (int kb = 0; kb < 8; ++kb)
            wf[u][kb] = *(const v8h*)(wr + kb * 32);
    }

    // ---------------- finisher constants ----------------
    float c4[4] = {0.f, 0.f, 0.f, 0.f};
    float xpr[4][4]; float bsum[4] = {0.f, 0.f, 0.f, 0.f};
    if (isFin) {
#pragma unroll
        for (int r = 0; r < 4; ++r) {
            int bt = w * 16 + q * 4 + r;
            c4[r] = c0[(l * 64 + bt) * 1024 + hs * 16 + lm];
        }
        if (l == 0) {
#pragma unroll
            for (int u = 0; u < 4; ++u)
#pragma unroll
                for (int r = 0; r < 4; ++r) {
                    int bt = w * 16 + q * 4 + r;
                    xpr[u][r] = xp0[bt * 4096 + u * 1024 + hs * 16 + lm];
                }
        } else {
#pragma unroll
            for (int u = 0; u < 4; ++u) {
                int g = u * 1024 + hs * 16 + lm;
                bsum[u] = b_ih[l * 4096 + g] + b_hh[l * 4096 + g];
            }
        }
    }
    float blv = 0.f;
    if (isFin && prj[4]) blv = blin[pcol[4] + lm];

    // ---------------- main pipelined loop ----------------
    for (int s = 0; s < NSTEPS; ++s) {
        const int rslot = (s + 1) & 1, wslot = s & 1;

        // early p-read (layer 1/2 finishers), hides L2/L3 latency behind MFMA
        float pv[4][4];
        const int tF = s - 2 * l;
        const bool finValid = isFin && ((unsigned)tF < 1024u);
        if (isFin && l >= 1 && finValid) {
            const _Float16* pr = pbuf + ((l - 1) * 2 + (s & 1)) * 262144 + hs * 16 + lm;
#pragma unroll
            for (int u = 0; u < 4; ++u)
#pragma unroll
                for (int r = 0; r < 4; ++r) {
                    int bt = w * 16 + q * 4 + r;
                    pv[u][r] = (float)pr[bt * 4096 + u * 1024];
                }
        }

        // ---- MFMA: all units, K-quarter per wave ----
        v4f acc[6][4];
        const v4f vz = {0.f, 0.f, 0.f, 0.f};
#pragma unroll
        for (int u = 0; u < 6; ++u)
#pragma unroll
            for (int j = 0; j < 4; ++j) acc[u][j] = vz;

        const _Float16* hPb = hbuf + (aselP * 2 + rslot) * 65536 + kofs;
        const _Float16* hSb = hbuf + (aselS * 2 + rslot) * 65536 + kofs;
#pragma unroll
        for (int kb = 0; kb < 8; ++kb) {
            v8h fp[4], fs[4];
#pragma unroll
            for (int j = 0; j < 4; ++j) {
                int mt = (w + j) & 3;                 // rotate: slot j <-> M-tile (w+j)&3
                fp[j] = *(const v8h*)(hPb + kb * 32 + (mt * 16 + lm) * 1024);
            }
            if (anyS) {
#pragma unroll
                for (int j = 0; j < 4; ++j) {
                    int mt = (w + j) & 3;
                    fs[j] = *(const v8h*)(hSb + kb * 32 + (mt * 16 + lm) * 1024);
                }
            }
#pragma unroll
            for (int u = 0; u < 6; ++u) {
                if (u >= nu) continue;
                if (!useS[u]) {
#pragma unroll
                    for (int j = 0; j < 4; ++j)
                        acc[u][j] = __builtin_amdgcn_mfma_f32_16x16x32_f16(fp[j], wf[u][kb], acc[u][j], 0, 0, 0);
                } else {
#pragma unroll
                    for (int j = 0; j < 4; ++j)
                        acc[u][j] = __builtin_amdgcn_mfma_f32_16x16x32_f16(fs[j], wf[u][kb], acc[u][j], 0, 0, 0);
                }
            }
        }

        // ---- cross-wave K reduction (2 LDS passes, 3 units each) ----
        // slot j=0 is this wave's kept M-tile (mt == w)
#pragma unroll
        for (int pass = 0; pass < 2; ++pass) {
            __syncthreads();
#pragma unroll
            for (int u3 = 0; u3 < 3; ++u3) {
                int u = pass * 3 + u3;
                if (u >= nu) continue;
#pragma unroll
                for (int j = 1; j < 4; ++j) {
                    int dst = (w + j) & 3;
                    red[((u3 * 4 + dst) * 4 + w) * 64 + ln] = acc[u][j];
                }
            }
            __syncthreads();
#pragma unroll
            for (int u3 = 0; u3 < 3; ++u3) {
                int u = pass * 3 + u3;
                if (u >= nu) continue;
#pragma unroll
                for (int sj = 1; sj < 4; ++sj) {
                    int src = (w + sj) & 3;
                    acc[u][0] += red[((u3 * 4 + w) * 4 + src) * 64 + ln];
                }
            }
        }

        // ---- epilogue: finisher (fused LSTM cell) ----
        if (finValid) {
            _Float16* hw = hbuf + (l * 2 + wslot) * 65536;
#pragma unroll
            for (int r = 0; r < 4; ++r) {
                int bt = w * 16 + q * 4 + r;
                float gi = acc[0][0][r], gf = acc[1][0][r], gg = acc[2][0][r], go = acc[3][0][r];
                if (l == 0) { gi += xpr[0][r]; gf += xpr[1][r]; gg += xpr[2][r]; go += xpr[3][r]; }
                else { gi += bsum[0] + pv[0][r]; gf += bsum[1] + pv[1][r];
                       gg += bsum[2] + pv[2][r]; go += bsum[3] + pv[3][r]; }
                gi = 1.f / (1.f + __expf(-gi));
                gf = 1.f / (1.f + __expf(-gf));
                go = 1.f / (1.f + __expf(-go));
                gg = 2.f / (1.f + __expf(-2.f * gg)) - 1.f;
                float c = gf * c4[r] + gi * gg;
                c4[r] = c;
                float th = 2.f / (1.f + __expf(-2.f * c)) - 1.f;
                hw[bt * 1024 + hs * 16 + lm] = (_Float16)(go * th);
            }
        }
        // ---- epilogue: singles (partials / projection) ----
#pragma unroll
        for (int u = 0; u < 6; ++u) {
            if (u >= nu) continue;
            if (isFin && u < 4) continue;
            if (s < lo[u] || s >= hi[u]) continue;
            if (prj[u]) {
                int t = s - 5;
#pragma unroll
                for (int r = 0; r < 4; ++r) {
                    int bt = w * 16 + q * 4 + r;
                    out[(bt * 1024 + t) * 64 + pcol[u] + lm] = acc[u][0][r] + blv;
                }
            } else {
                _Float16* pw = pbuf + (pl[u] * 2 + ((s + 1) & 1)) * 262144;
#pragma unroll
                for (int r = 0; r < 4; ++r) {
                    int bt = w * 16 + q * 4 + r;
                    pw[bt * 4096 + pcol[u] + lm] = (_Float16)acc[u][0][r];
                }
            }
        }

        // ---- grid barrier (release -> arrive -> spin -> acquire) ----
        __threadfence();
        __syncthreads();
        if (tid == 0) {
            __hip_atomic_fetch_add(cnt, 1u, __ATOMIC_RELAXED, __HIP_MEMORY_SCOPE_AGENT);
            unsigned tgt = 256u * (unsigned)(s + 1);
            while (__hip_atomic_load(cnt, __ATOMIC_RELAXED, __HIP_MEMORY_SCOPE_AGENT) < tgt)
                __builtin_amdgcn_s_sleep(2);
        }
        __syncthreads();
        __threadfence();
    }
}

extern "C" void kernel_launch(void* const* d_in, const int* in_sizes, int n_in,
                              void* d_out, int out_size, void* d_ws, size_t ws_size,
                              hipStream_t stream) {
    const float* enc   = (const float*)d_in[0];
    const float* h0    = (const float*)d_in[1];
    const float* c0    = (const float*)d_in[2];
    const float* W_ih  = (const float*)d_in[3];
    const float* W_hh  = (const float*)d_in[4];
    const float* b_ih  = (const float*)d_in[5];
    const float* b_hh  = (const float*)d_in[6];
    const float* W_lin = (const float*)d_in[7];
    const float* b_lin = (const float*)d_in[8];
    float* out = (float*)d_out;
    char* ws = (char*)d_ws;

    // ws layout (bytes), total ~54.5 MB
    _Float16* Wih16  = (_Float16*)(ws);                 // 25165824
    _Float16* Whh16  = (_Float16*)(ws + 25165824);      // 25165824
    _Float16* Wlin16 = (_Float16*)(ws + 50331648);      // 131072
    _Float16* enc16  = (_Float16*)(ws + 50462720);      // 131072
    float*    xp0    = (float*)   (ws + 50593792);      // 1048576
    _Float16* hbuf   = (_Float16*)(ws + 51642368);      // 786432
    _Float16* pbuf   = (_Float16*)(ws + 52428800);      // 2097152
    unsigned* cnt    = (unsigned*)(ws + 54525952);      // 64

    cvt4_kernel<<<2048, 256, 0, stream>>>(W_ih, Wih16, 3145728);
    cvt4_kernel<<<2048, 256, 0, stream>>>(W_hh, Whh16, 3145728);
    cvt4_kernel<<<64, 256, 0, stream>>>(W_lin, Wlin16, 16384);
    cvt4_kernel<<<64, 256, 0, stream>>>(enc, enc16, 16384);
    hinit_kernel<<<768, 256, 0, stream>>>(h0, hbuf);
    xp0_kernel<<<64, 256, 0, stream>>>(enc16, Wih16, b_ih, b_hh, xp0);
    zcnt_kernel<<<1, 64, 0, stream>>>(cnt);

    lstm_persist<<<256, 256, 0, stream>>>(Wih16, Whh16, Wlin16, xp0, b_ih, b_hh,
                                          c0, b_lin, hbuf, pbuf, out, cnt);
}

// Round 3
// 14741.130 us; speedup vs baseline: 5.0837x; 5.0837x over previous
//
#include <hip/hip_runtime.h>
#include <hip/hip_bf16.h>
#include <hip/hip_fp16.h>

// Persistent pipelined LSTM decoder. B=64, E=H=1024, 4H=4096, T=1024, L=3, O=64.
// 256 blocks x 256 threads, weights register/LDS-resident, flag-tree barrier,
// write-through (sc0 sc1) producer stores + one acquire-inv per step.

typedef _Float16 v8h __attribute__((ext_vector_type(8)));
typedef _Float16 v4h __attribute__((ext_vector_type(4)));
typedef float v4f __attribute__((ext_vector_type(4)));

#define NSTEPS 1029
#define AGG 192

__device__ inline void store16_wt(void* p, v8h v) {
    asm volatile("global_store_dwordx4 %0, %1, off sc0 sc1" :: "v"(p), "v"(v) : "memory");
}
__device__ inline void store8_wt(void* p, unsigned long long v) {
    asm volatile("global_store_dwordx2 %0, %1, off sc0 sc1" :: "v"(p), "v"(v) : "memory");
}

__global__ void cvt4_kernel(const float* __restrict__ s, _Float16* __restrict__ d, int n4) {
    int i = blockIdx.x * blockDim.x + threadIdx.x;
    int stride = gridDim.x * blockDim.x;
    for (; i < n4; i += stride) {
        v4f v = ((const v4f*)s)[i];
        v4h o;
        o[0] = (_Float16)v[0]; o[1] = (_Float16)v[1];
        o[2] = (_Float16)v[2]; o[3] = (_Float16)v[3];
        ((v4h*)d)[i] = o;
    }
}

// hbuf [3 layer][2 slot][64 b][1024 j] f16; slot1 = h[-1]
__global__ void hinit_kernel(const float* __restrict__ h0, _Float16* __restrict__ hbuf) {
    int i = blockIdx.x * 256 + threadIdx.x;   // 768*256 = 196608
    int l = i >> 16, rem = i & 65535;
    hbuf[(l * 2 + 1) * 65536 + rem] = (_Float16)h0[i];
}

__global__ void zflags_kernel(unsigned* f) { int i = threadIdx.x; if (i < 260) f[i] = 0u; }

// xp0[b][g] = enc @ Wih0^T + b_ih0 + b_hh0  (validated in R1/R2)
__global__ __launch_bounds__(256) void xp0_kernel(
    const _Float16* __restrict__ enc16, const _Float16* __restrict__ Wih,
    const float* __restrict__ b_ih, const float* __restrict__ b_hh,
    float* __restrict__ xp0) {
    __shared__ float red[16384];
    const int tid = threadIdx.x, bx = blockIdx.x;
    const int ln = tid & 63, w = tid >> 6, lm = ln & 15, q = ln >> 4;
    v4f acc[4][4] = {};
    for (int kb = 0; kb < 8; ++kb) {
        int kk = (w + 4 * kb) * 32 + q * 8;
        v8h af[4], bf[4];
#pragma unroll
        for (int mt = 0; mt < 4; ++mt) af[mt] = *(const v8h*)(enc16 + (mt * 16 + lm) * 1024 + kk);
#pragma unroll
        for (int nt = 0; nt < 4; ++nt) bf[nt] = *(const v8h*)(Wih + (bx * 64 + nt * 16 + lm) * 1024 + kk);
#pragma unroll
        for (int mt = 0; mt < 4; ++mt)
#pragma unroll
            for (int nt = 0; nt < 4; ++nt)
                acc[mt][nt] = __builtin_amdgcn_mfma_f32_16x16x32_f16(af[mt], bf[nt], acc[mt][nt], 0, 0, 0);
    }
#pragma unroll
    for (int mt = 0; mt < 4; ++mt) if (mt != w)
#pragma unroll
        for (int nt = 0; nt < 4; ++nt)
            *(v4f*)&red[((w * 16 + mt * 4 + nt) * 64 + ln) * 4] = acc[mt][nt];
    __syncthreads();
#pragma unroll
    for (int ww = 0; ww < 4; ++ww) if (ww != w)
#pragma unroll
        for (int nt = 0; nt < 4; ++nt)
            acc[w][nt] += *(const v4f*)&red[((ww * 16 + w * 4 + nt) * 64 + ln) * 4];
#pragma unroll
    for (int nt = 0; nt < 4; ++nt) {
        int g = bx * 64 + nt * 16 + lm;
        float bb = b_ih[g] + b_hh[g];
#pragma unroll
        for (int r = 0; r < 4; ++r) {
            int b = w * 16 + q * 4 + r;
            xp0[b * 4096 + g] = acc[w][nt][r] + bb;
        }
    }
}

__global__ __launch_bounds__(256, 1) void lstm_persist(
    const _Float16* __restrict__ Wih16,   // [3][4096][1024]
    const _Float16* __restrict__ Whh16,   // [3][4096][1024]
    const _Float16* __restrict__ Wlin16,  // [64][1024]
    const float* __restrict__ xp0,        // [64][4096]
    const float* __restrict__ b_ih,
    const float* __restrict__ b_hh,
    const float* __restrict__ c0,         // [3][64][1024]
    const float* __restrict__ blin,       // [64]
    _Float16* __restrict__ hbuf,          // [3][2][64][1024]
    _Float16* __restrict__ pbuf,          // [2 lp][2 slot][4096 g][64 b]
    float* __restrict__ out,              // [64][1024][64]
    unsigned* __restrict__ flags,         // [256]
    unsigned* __restrict__ go)
{
    __shared__ v4f red[2][12][64];      // 24 KB exchange (12 = used (dst,src) pairs)
    __shared__ _Float16 ldsW[16384];    // 32 KB: 6th unit's 16x1024 weight tile
    const int b = blockIdx.x, tid = threadIdx.x;
    const int ln = tid & 63, w = tid >> 6, lm = ln & 15, q = ln >> 4;
    const int bt0 = w * 16 + q * 4;

    // ---------------- role resolution (uniform) ----------------
    const bool isFin = b < 192;
    const int l = b >> 6, hs = b & 63;
    int sidR[5], sidL; bool hasL;
    if (isFin) {
        hasL = true;
        sidR[0] = sidR[1] = sidR[2] = sidR[3] = -1; sidR[4] = -2;
        int s4;
        if (b < 64) s4 = b;                        // G1 tile b       (asel 0 == l)
        else if (b < 128) s4 = 256 + (b - 64);     // G3 tile b-64    (asel 1 == l)
        else if (b < 132) s4 = 512 + (b - 128);    // proj tile       (asel 2 == l)
        else s4 = 64 + (b - 132);                  // G1 tiles 64..123 (asel 0 != l=2)
        sidL = s4;
    } else {
        int j = b - 192;
        int i0 = (j < 60) ? 5 * j : 300 + 6 * (j - 60);
        hasL = (j >= 60);
        // pool singles list: [G1 124..255] ++ [G3 64..255]  (324 ids)
#pragma unroll
        for (int u = 0; u < 5; ++u) { int id = i0 + u; sidR[u] = (id < 132) ? 124 + id : 188 + id; }
        sidL = hasL ? 188 + i0 + 5 : -2;
    }

    const _Float16* wb[6]; int asel[6], lo[6], hi[6], pcol[6], pl[6]; bool prj[6], act[6];
#pragma unroll
    for (int m = 0; m < 6; ++m) {
        int sd = (m < 5) ? sidR[m] : sidL;
        act[m] = (isFin && m < 4) || sd >= 0;
        prj[m] = false; pl[m] = 0; pcol[m] = 0;
        if (isFin && m < 4) {
            wb[m] = Whh16 + l * 4194304 + (m * 1024 + hs * 16) * 1024;
            asel[m] = l; lo[m] = 1 << 30; hi[m] = 0;      // no single-store path
        } else if (sd >= 512) {       // proj: Wlin, A=h2
            wb[m] = Wlin16 + (sd - 512) * 16384;
            asel[m] = 2; lo[m] = 5; hi[m] = 1029; prj[m] = true; pcol[m] = (sd - 512) * 16;
        } else if (sd >= 256) {       // G3: Wih layer2, A=h1
            wb[m] = Wih16 + 2 * 4194304 + (sd - 256) * 16384;
            asel[m] = 1; lo[m] = 3; hi[m] = 1027; pl[m] = 1; pcol[m] = (sd - 256) * 16;
        } else if (sd >= 0) {         // G1: Wih layer1, A=h0
            wb[m] = Wih16 + 4194304 + sd * 16384;
            asel[m] = 0; lo[m] = 1; hi[m] = 1025; pl[m] = 0; pcol[m] = sd * 16;
        } else {
            wb[m] = wb[0]; asel[m] = 0; lo[m] = 1 << 30; hi[m] = 0;
        }
    }
    const int aselP = asel[0];
    int aselS = aselP; bool useS[6]; bool anyS = false;
#pragma unroll
    for (int m = 0; m < 6; ++m) {
        if (!act[m]) asel[m] = aselP;
        useS[m] = (asel[m] != aselP);
        if (useS[m]) { aselS = asel[m]; anyS = true; }
    }

    // ---------------- weights -> registers / LDS (once) ----------------
    const int kofs = w * 256 + q * 8;   // this wave's K-quarter
    v8h wf[5][8];
#pragma unroll
    for (int m = 0; m < 5; ++m) {
        const _Float16* wr = wb[m] + lm * 1024 + kofs;
#pragma unroll
        for (int kb = 0; kb < 8; ++kb) wf[m][kb] = *(const v8h*)(wr + kb * 32);
    }
    if (hasL) {
        const _Float16* wr = wb[5];
        for (int it = tid; it < 2048; it += 256)
            *(v8h*)&ldsW[it * 8] = *(const v8h*)(wr + it * 8);
    }
    __syncthreads();

    // ---------------- finisher constants ----------------
    float c4[4] = {0.f, 0.f, 0.f, 0.f};
    float xpr[4][4]; float bsum[4] = {0.f, 0.f, 0.f, 0.f};
    if (isFin) {
#pragma unroll
        for (int r = 0; r < 4; ++r)
            c4[r] = c0[(l * 64 + bt0 + r) * 1024 + hs * 16 + lm];
        if (l == 0) {
#pragma unroll
            for (int u = 0; u < 4; ++u)
#pragma unroll
                for (int r = 0; r < 4; ++r)
                    xpr[u][r] = xp0[(bt0 + r) * 4096 + u * 1024 + hs * 16 + lm];
        } else {
#pragma unroll
            for (int u = 0; u < 4; ++u) {
                int g = u * 1024 + hs * 16 + lm;
                bsum[u] = b_ih[l * 4096 + g] + b_hh[l * 4096 + g];
            }
        }
    }
    float blv = 0.f;
    if (hasL && prj[5]) blv = blin[pcol[5] + lm];

    // ---------------- main loop ----------------
    for (int s = 0; s < NSTEPS; ++s) {
        const unsigned su = (unsigned)(s + 1);
        const int rslot = (s + 1) & 1, wslot = s & 1;
        const int tF = s - 2 * l;
        const bool finValid = isFin && ((unsigned)tF < 1024u);

        // early p-read (layers 1/2), [g][b] layout -> 8B vector loads
        float pv[4][4];
        if (isFin && l >= 1 && finValid) {
            const _Float16* pr = pbuf + ((l - 1) * 2 + (s & 1)) * 262144;
#pragma unroll
            for (int u = 0; u < 4; ++u) {
                v4h t4 = *(const v4h*)&pr[(u * 1024 + hs * 16 + lm) * 64 + bt0];
#pragma unroll
                for (int r = 0; r < 4; ++r) pv[u][r] = (float)t4[r];
            }
        }

        v4f accR[5][4], accL[4];
        const v4f vz = {0.f, 0.f, 0.f, 0.f};
#pragma unroll
        for (int m = 0; m < 5; ++m)
#pragma unroll
            for (int j = 0; j < 4; ++j) accR[m][j] = vz;
#pragma unroll
        for (int j = 0; j < 4; ++j) accL[j] = vz;

        const _Float16* hPb = hbuf + (aselP * 2 + rslot) * 65536 + kofs;
        const _Float16* hSb = hbuf + (aselS * 2 + rslot) * 65536 + kofs;
#pragma unroll
        for (int kb = 0; kb < 8; ++kb) {
            v8h fp[4], fs[4];
#pragma unroll
            for (int j = 0; j < 4; ++j) {
                int mt = (w + j) & 3;                 // rotated M-tile assignment
                fp[j] = *(const v8h*)(hPb + kb * 32 + (mt * 16 + lm) * 1024);
            }
            if (anyS) {
#pragma unroll
                for (int j = 0; j < 4; ++j) {
                    int mt = (w + j) & 3;
                    fs[j] = *(const v8h*)(hSb + kb * 32 + (mt * 16 + lm) * 1024);
                }
            } else {
#pragma unroll
                for (int j = 0; j < 4; ++j) fs[j] = fp[j];
            }
            v8h wl;
            if (hasL) wl = *(const v8h*)&ldsW[lm * 1024 + kofs + kb * 32];
#pragma unroll
            for (int m = 0; m < 5; ++m) {
                if (!act[m]) continue;
#pragma unroll
                for (int j = 0; j < 4; ++j)
                    accR[m][j] = __builtin_amdgcn_mfma_f32_16x16x32_f16(useS[m] ? fs[j] : fp[j], wf[m][kb], accR[m][j], 0, 0, 0);
            }
            if (hasL)
#pragma unroll
                for (int j = 0; j < 4; ++j)
                    accL[j] = __builtin_amdgcn_mfma_f32_16x16x32_f16(useS[5] ? fs[j] : fp[j], wl, accL[j], 0, 0, 0);
        }

        // ---- cross-wave K reduction: 3 passes x 2 units ----
#pragma unroll
        for (int p = 0; p < 3; ++p) {
            __syncthreads();
            {   int m = 2 * p;
                if (act[m])
#pragma unroll
                    for (int j = 1; j < 4; ++j) {
                        int dst = (w + j) & 3;
                        red[0][dst * 3 + w - (w > dst ? 1 : 0)][ln] = accR[m][j];
                    }
            }
            if (p < 2) {
                int m = 2 * p + 1;
                if (act[m])
#pragma unroll
                    for (int j = 1; j < 4; ++j) {
                        int dst = (w + j) & 3;
                        red[1][dst * 3 + w - (w > dst ? 1 : 0)][ln] = accR[m][j];
                    }
            } else if (hasL) {
#pragma unroll
                for (int j = 1; j < 4; ++j) {
                    int dst = (w + j) & 3;
                    red[1][dst * 3 + w - (w > dst ? 1 : 0)][ln] = accL[j];
                }
            }
            __syncthreads();
            {   int m = 2 * p;
                if (act[m])
#pragma unroll
                    for (int sj = 1; sj < 4; ++sj) {
                        int src = (w + sj) & 3;
                        accR[m][0] += red[0][w * 3 + src - (src > w ? 1 : 0)][ln];
                    }
            }
            if (p < 2) {
                int m = 2 * p + 1;
                if (act[m])
#pragma unroll
                    for (int sj = 1; sj < 4; ++sj) {
                        int src = (w + sj) & 3;
                        accR[m][0] += red[1][w * 3 + src - (src > w ? 1 : 0)][ln];
                    }
            } else if (hasL) {
#pragma unroll
                for (int sj = 1; sj < 4; ++sj) {
                    int src = (w + sj) & 3;
                    accL[0] += red[1][w * 3 + src - (src > w ? 1 : 0)][ln];
                }
            }
        }

        // ---- finisher epilogue: LSTM cell + LDS transpose + 16B WT stores ----
        if (isFin) {
            float hv[4];
            if (finValid) {
#pragma unroll
                for (int r = 0; r < 4; ++r) {
                    float gi = accR[0][0][r], gf = accR[1][0][r], gg = accR[2][0][r], go_ = accR[3][0][r];
                    if (l == 0) { gi += xpr[0][r]; gf += xpr[1][r]; gg += xpr[2][r]; go_ += xpr[3][r]; }
                    else { gi += bsum[0] + pv[0][r]; gf += bsum[1] + pv[1][r];
                           gg += bsum[2] + pv[2][r]; go_ += bsum[3] + pv[3][r]; }
                    gi = 1.f / (1.f + __expf(-gi));
                    gf = 1.f / (1.f + __expf(-gf));
                    go_ = 1.f / (1.f + __expf(-go_));
                    gg = 2.f / (1.f + __expf(-2.f * gg)) - 1.f;
                    float c = gf * c4[r] + gi * gg;
                    c4[r] = c;
                    float th = 2.f / (1.f + __expf(-2.f * c)) - 1.f;
                    hv[r] = go_ * th;
                }
            }
            __syncthreads();                       // red reuse as h-transpose tile
            _Float16* hsh = (_Float16*)red;        // [64][16]
            if (finValid)
#pragma unroll
                for (int r = 0; r < 4; ++r) hsh[(bt0 + r) * 16 + lm] = (_Float16)hv[r];
            __syncthreads();
            if (finValid && tid < 128) {
                int row = tid >> 1, half = tid & 1;
                v8h hv8 = *(v8h*)&hsh[row * 16 + half * 8];
                store16_wt(hbuf + (l * 2 + wslot) * 65536 + row * 1024 + hs * 16 + half * 8, hv8);
            }
        }

        // ---- singles epilogue: p-partials (8B WT) / projection ----
#pragma unroll
        for (int m = 0; m < 6; ++m) {
            if (isFin && m < 4) continue;
            if (!act[m]) continue;
            if (s < lo[m] || s >= hi[m]) continue;
            v4f a = (m < 5) ? accR[m][0] : accL[0];
            if (prj[m]) {
                int t = s - 5;
#pragma unroll
                for (int r = 0; r < 4; ++r)
                    out[((bt0 + r) * 1024 + t) * 64 + pcol[m] + lm] = a[r] + blv;
            } else {
                union { unsigned long long u64; _Float16 h4[4]; } pk;
#pragma unroll
                for (int r = 0; r < 4; ++r) pk.h4[r] = (_Float16)a[r];
                store8_wt(pbuf + (pl[m] * 2 + ((s + 1) & 1)) * 262144 + (pcol[m] + lm) * 64 + bt0, pk.u64);
            }
        }

        // ---- barrier: waitcnt-release, flag store, aggregate, go, acquire ----
        asm volatile("s_waitcnt vmcnt(0)" ::: "memory");
        __syncthreads();
        if (tid == 0)
            __hip_atomic_store(&flags[b], su, __ATOMIC_RELAXED, __HIP_MEMORY_SCOPE_AGENT);
        if (b == AGG) {
            unsigned v;
            do {
                v = __hip_atomic_load(&flags[tid], __ATOMIC_RELAXED, __HIP_MEMORY_SCOPE_AGENT);
            } while (v < su);
            __syncthreads();
            if (tid == 0)
                __hip_atomic_store(go, su, __ATOMIC_RELAXED, __HIP_MEMORY_SCOPE_AGENT);
        }
        if (tid == 0) {
            while (__hip_atomic_load(go, __ATOMIC_RELAXED, __HIP_MEMORY_SCOPE_AGENT) < su)
                __builtin_amdgcn_s_sleep(1);
            (void)__hip_atomic_load(go, __ATOMIC_ACQUIRE, __HIP_MEMORY_SCOPE_AGENT);  // one buffer_inv
        }
        __syncthreads();
    }
}

extern "C" void kernel_launch(void* const* d_in, const int* in_sizes, int n_in,
                              void* d_out, int out_size, void* d_ws, size_t ws_size,
                              hipStream_t stream) {
    const float* enc   = (const float*)d_in[0];
    const float* h0    = (const float*)d_in[1];
    const float* c0    = (const float*)d_in[2];
    const float* W_ih  = (const float*)d_in[3];
    const float* W_hh  = (const float*)d_in[4];
    const float* b_ih  = (const float*)d_in[5];
    const float* b_hh  = (const float*)d_in[6];
    const float* W_lin = (const float*)d_in[7];
    const float* b_lin = (const float*)d_in[8];
    float* out = (float*)d_out;
    char* ws = (char*)d_ws;

    _Float16* Wih16  = (_Float16*)(ws);                 // 25165824 B
    _Float16* Whh16  = (_Float16*)(ws + 25165824);      // 25165824 B
    _Float16* Wlin16 = (_Float16*)(ws + 50331648);      // 131072 B
    _Float16* enc16  = (_Float16*)(ws + 50462720);      // 131072 B (reused: flags after xp0)
    float*    xp0    = (float*)   (ws + 50593792);      // 1048576 B
    _Float16* hbuf   = (_Float16*)(ws + 51642368);      // 786432 B
    _Float16* pbuf   = (_Float16*)(ws + 52428800);      // 2097152 B
    unsigned* flags  = (unsigned*)(ws + 50462720);      // aliases enc16 (dead after xp0)
    unsigned* go     = flags + 256;

    cvt4_kernel<<<2048, 256, 0, stream>>>(W_ih, Wih16, 3145728);
    cvt4_kernel<<<2048, 256, 0, stream>>>(W_hh, Whh16, 3145728);
    cvt4_kernel<<<64, 256, 0, stream>>>(W_lin, Wlin16, 16384);
    cvt4_kernel<<<64, 256, 0, stream>>>(enc, enc16, 16384);
    hinit_kernel<<<768, 256, 0, stream>>>(h0, hbuf);
    xp0_kernel<<<64, 256, 0, stream>>>(enc16, Wih16, b_ih, b_hh, xp0);
    zflags_kernel<<<1, 512, 0, stream>>>(flags);   // after xp0: enc16 region is dead

    lstm_persist<<<256, 256, 0, stream>>>(Wih16, Whh16, Wlin16, xp0, b_ih, b_hh,
                                          c0, b_lin, hbuf, pbuf, out, flags, go);
}